// Round 7
// baseline (302.447 us; speedup 1.0000x reference)
//
#include <hip/hip_runtime.h>

// SparseDopplerAttention on gfx950 — R7: 3-kernel split + register pipelining.
// Identity (R3): out[q] = (sum_k P[q,k]*vsum[k])/(sum_k P[q,k]) + sum(bv),
//   vsum[k] = x[k].colsum(Wv) in fp32; V GEMM and PV GEMM eliminated.
// K0 colsum: colsum(Wv)[96] + sum(bv) -> wvs (1 block).
// K1 proj:   K (bf16 fragment-major) + vsum -> d_ws. 512x512thr, 0 LDS,
//            block = half*256+range so writer XCD == reader XCD (L2 handoff).
// K2 attn:   grid-capped 50% occupancy (4 blk/CU); the R6 L2-latency stall is
//            hidden by distance-1 double-buffered REGISTER prefetch of the
//            K tile + vsum (even/odd bodies, no rotation copies). VGPR ~110
//            under the (256,4) cap of 128 — free, since grid caps waves anyway.

#define SCALE 0.18033688011112042f   // log2(e)/8

typedef __bf16 bf16;
typedef bf16 v4bf __attribute__((ext_vector_type(4)));
typedef bf16 v8bf __attribute__((ext_vector_type(8)));
typedef float v4f __attribute__((ext_vector_type(4)));

static __device__ __forceinline__ v8bf pk8(float4 a, float4 b) {
    v8bf r;
    r[0] = (bf16)a.x; r[1] = (bf16)a.y; r[2] = (bf16)a.z; r[3] = (bf16)a.w;
    r[4] = (bf16)b.x; r[5] = (bf16)b.y; r[6] = (bf16)b.z; r[7] = (bf16)b.w;
    return r;
}
static __device__ __forceinline__ float d4(float4 a, const float* w) {
    return a.x * w[0] + a.y * w[1] + a.z * w[2] + a.w * w[3];
}

// =================== K0: colsum(Wv) + sum(bv) ===================
__global__ void sda_colsum(const float* __restrict__ Wv,
                           const float* __restrict__ bv,
                           float* __restrict__ wvs)
{
    int t = threadIdx.x;
    if (t < 96) {
        float s0 = 0.f, s1 = 0.f, s2 = 0.f, s3 = 0.f;
#pragma unroll
        for (int r = 0; r < 64; r += 4) {
            s0 += Wv[r * 96 + t];
            s1 += Wv[(r + 1) * 96 + t];
            s2 += Wv[(r + 2) * 96 + t];
            s3 += Wv[(r + 3) * 96 + t];
        }
        wvs[t] = (s0 + s1) + (s2 + s3);
    } else if (t == 96) {
        float s = 0.f;
#pragma unroll
        for (int d = 0; d < 64; d++) s += bv[d];
        wvs[96] = s;
    }
}

// =================== K1: K projection + vsum ===================
// 512 blocks x 512 thr (2 blk/CU); block = half*256 + range; wave owns 32 rows.
// K layout (within range): key*128 + (dim/8)*16 + (dim%8)*2  (fragment-major).
__global__ __launch_bounds__(512, 4)
void sda_proj(const float* __restrict__ power,
              const int*   __restrict__ ele_i,
              const int*   __restrict__ azi_i,
              const float* __restrict__ ele_t,
              const float* __restrict__ azi_t,
              const float* __restrict__ Wk, const float* __restrict__ bk,
              const float* __restrict__ wvs,
              char* __restrict__ Kf, float* __restrict__ vsg)
{
    const int tid  = threadIdx.x;
    const int wave = tid >> 6;
    const int lane = tid & 63;
    const int l15  = lane & 15;
    const int quad = lane >> 4;
    const int range = blockIdx.x & 255;
    const int half  = blockIdx.x >> 8;
    const int rloc0 = half * 256 + wave * 32;          // block-local key base
    const int krow0 = range * 512 + rloc0;             // global row base

    // x fragments (bf16) + fp32 vsum for this wave's 32 rows
    v8bf xa[2][3];
#pragma unroll
    for (int mt = 0; mt < 2; mt++) {
        int row = krow0 + mt * 16 + l15;
        const float* pr = power + (size_t)row * 64;
        float4 a0 = *(const float4*)(pr + quad * 8);
        float4 a1 = *(const float4*)(pr + quad * 8 + 4);
        float dd = d4(a0, wvs + quad * 8) + d4(a1, wvs + quad * 8 + 4);
        xa[mt][0] = pk8(a0, a1);
        a0 = *(const float4*)(pr + 32 + quad * 8);
        a1 = *(const float4*)(pr + 32 + quad * 8 + 4);
        dd += d4(a0, wvs + 32 + quad * 8) + d4(a1, wvs + 32 + quad * 8 + 4);
        xa[mt][1] = pk8(a0, a1);
        int ie = ele_i[row];
        int ia = azi_i[row];
        const float* tb = (quad < 2) ? (ele_t + ie * 16 + quad * 8)
                                     : (azi_t + ia * 16 + (quad - 2) * 8);
        a0 = *(const float4*)tb;
        a1 = *(const float4*)(tb + 4);
        dd += d4(a0, wvs + 64 + quad * 8) + d4(a1, wvs + 64 + quad * 8 + 4);
        xa[mt][2] = pk8(a0, a1);
        dd += __shfl_xor(dd, 16);
        dd += __shfl_xor(dd, 32);
        if (quad == 0) vsg[krow0 + mt * 16 + l15] = dd;
    }

    // K^T = Wk @ x^T (operand swap: col=l15=key, row=quad*4+r=dim), b64 stores
    char* kr = Kf + (size_t)range * 65536;
#pragma unroll
    for (int mtd = 0; mtd < 4; mtd++) {
        v4f acc0 = {0.f, 0.f, 0.f, 0.f};
        v4f acc1 = {0.f, 0.f, 0.f, 0.f};
#pragma unroll
        for (int kt = 0; kt < 3; kt++) {
            const float* p = Wk + (mtd * 16 + l15) * 96 + kt * 32 + quad * 8;
            v8bf wk = pk8(*(const float4*)p, *(const float4*)(p + 4));
            acc0 = __builtin_amdgcn_mfma_f32_16x16x32_bf16(wk, xa[0][kt], acc0, 0, 0, 0);
            acc1 = __builtin_amdgcn_mfma_f32_16x16x32_bf16(wk, xa[1][kt], acc1, 0, 0, 0);
        }
        float4 bk4 = *(const float4*)(bk + mtd * 16 + quad * 4);
#pragma unroll
        for (int ntr = 0; ntr < 2; ntr++) {
            v4f acc = ntr ? acc1 : acc0;
            int keyb = rloc0 + ntr * 16 + l15;
            v4bf o;
            o[0] = (bf16)(acc[0] + bk4.x);
            o[1] = (bf16)(acc[1] + bk4.y);
            o[2] = (bf16)(acc[2] + bk4.z);
            o[3] = (bf16)(acc[3] + bk4.w);
            *(v4bf*)(kr + keyb * 128 + (((mtd * 2 + (quad >> 1)) << 4) | ((quad & 1) << 3))) = o;
        }
    }
}

// =================== K2: attention ===================
static __device__ __forceinline__ void ld_tile(const char* kr, const float* vsr,
                                               int t, int l15, int quad,
                                               v8bf kf[2][2], v4f vs[2])
{
#pragma unroll
    for (int mtk = 0; mtk < 2; mtk++) {
#pragma unroll
        for (int kt = 0; kt < 2; kt++) {
            int key = t * 32 + mtk * 16 + l15;
            kf[mtk][kt] = *(const v8bf*)(kr + key * 128 + kt * 64 + quad * 16);
        }
        vs[mtk] = *(const v4f*)(vsr + t * 32 + mtk * 16 + quad * 4);
    }
}
static __device__ __forceinline__ void tile_compute(const v8bf kf[2][2], const v4f vs[2],
                                                    const v8bf qf[2][2],
                                                    float* osum, float* lsum)
{
#pragma unroll
    for (int mtk = 0; mtk < 2; mtk++)
#pragma unroll
        for (int nt = 0; nt < 2; nt++) {
            v4f acc = {0.f, 0.f, 0.f, 0.f};
            acc = __builtin_amdgcn_mfma_f32_16x16x32_bf16(kf[mtk][0], qf[nt][0], acc, 0, 0, 0);
            acc = __builtin_amdgcn_mfma_f32_16x16x32_bf16(kf[mtk][1], qf[nt][1], acc, 0, 0, 0);
            float p0 = __builtin_amdgcn_exp2f(acc[0]);
            float p1 = __builtin_amdgcn_exp2f(acc[1]);
            float p2 = __builtin_amdgcn_exp2f(acc[2]);
            float p3 = __builtin_amdgcn_exp2f(acc[3]);
            lsum[nt] += (p0 + p1) + (p2 + p3);
            osum[nt] += ((p0 * vs[mtk][0] + p1 * vs[mtk][1]) +
                         (p2 * vs[mtk][2] + p3 * vs[mtk][3]));
        }
}

// 1024 blocks x 256 thr; block = qc*256 + range (range's 4 blocks on one XCD).
__global__ __launch_bounds__(256, 4)
void sda_attn(const float* __restrict__ power,
              const int*   __restrict__ ele_i,
              const int*   __restrict__ azi_i,
              const float* __restrict__ ele_t,
              const float* __restrict__ azi_t,
              const float* __restrict__ Wq, const float* __restrict__ bq,
              const float* __restrict__ wvs,
              const char* __restrict__ Kf, const float* __restrict__ vsg,
              float* __restrict__ out)
{
    __shared__ char sq[4][4096];   // per-wave Q-transpose scratch

    const int tid  = threadIdx.x;
    const int wave = tid >> 6;
    const int lane = tid & 63;
    const int l15  = lane & 15;
    const int quad = lane >> 4;
    const int range = blockIdx.x & 255;
    const int qc    = blockIdx.x >> 8;
    const int qrow0 = range * 512 + qc * 128 + wave * 32;

    const float bvs = wvs[96];

    // x fragments for this wave's 32 queries
    v8bf xq[2][3];
#pragma unroll
    for (int nt = 0; nt < 2; nt++) {
        int row = qrow0 + nt * 16 + l15;
        const float* pr = power + (size_t)row * 64;
        xq[nt][0] = pk8(*(const float4*)(pr + quad * 8), *(const float4*)(pr + quad * 8 + 4));
        xq[nt][1] = pk8(*(const float4*)(pr + 32 + quad * 8), *(const float4*)(pr + 32 + quad * 8 + 4));
        int ie = ele_i[row];
        int ia = azi_i[row];
        const float* tb = (quad < 2) ? (ele_t + ie * 16 + quad * 8)
                                     : (azi_t + ia * 16 + (quad - 2) * 8);
        xq[nt][2] = pk8(*(const float4*)tb, *(const float4*)(tb + 4));
    }

    // Q^T = Wq @ xq^T, fold SCALE, transpose via own scratch (validated R3-R6)
    char* Sw = sq[wave];
#pragma unroll
    for (int mtd = 0; mtd < 4; mtd++) {
        v4f acc0 = {0.f, 0.f, 0.f, 0.f};
        v4f acc1 = {0.f, 0.f, 0.f, 0.f};
#pragma unroll
        for (int kt = 0; kt < 3; kt++) {
            const float* p = Wq + (mtd * 16 + l15) * 96 + kt * 32 + quad * 8;
            v8bf wq = pk8(*(const float4*)p, *(const float4*)(p + 4));
            acc0 = __builtin_amdgcn_mfma_f32_16x16x32_bf16(wq, xq[0][kt], acc0, 0, 0, 0);
            acc1 = __builtin_amdgcn_mfma_f32_16x16x32_bf16(wq, xq[1][kt], acc1, 0, 0, 0);
        }
        float4 bq4 = *(const float4*)(bq + mtd * 16 + quad * 4);
#pragma unroll
        for (int nt = 0; nt < 2; nt++) {
            v4f acc = nt ? acc1 : acc0;
            int row = nt * 16 + l15;
            v4bf o;
            o[0] = (bf16)((acc[0] + bq4.x) * SCALE);
            o[1] = (bf16)((acc[1] + bq4.y) * SCALE);
            o[2] = (bf16)((acc[2] + bq4.z) * SCALE);
            o[3] = (bf16)((acc[3] + bq4.w) * SCALE);
            *(v4bf*)(Sw + row * 128 +
                     ((((mtd * 2 + (quad >> 1)) ^ (row & 7)) << 4) | ((quad & 1) << 3))) = o;
        }
    }
    v8bf qf[2][2];
#pragma unroll
    for (int nt = 0; nt < 2; nt++)
#pragma unroll
        for (int kt = 0; kt < 2; kt++)
            qf[nt][kt] = *(const v8bf*)(Sw + (nt * 16 + l15) * 128 +
                                        (((kt * 4 + quad) ^ (l15 & 7)) << 4));

    // Phase B: S^T = K @ Q^T (log2 domain), exp2, weighted accumulate.
    // Distance-1 register double-buffer (even/odd bodies, no copies).
    const char*  kr  = Kf + (size_t)range * 65536;
    const float* vsr = vsg + range * 512;
    float osum[2] = {0.f, 0.f};
    float lsum[2] = {0.f, 0.f};

    v8bf kA[2][2], kB[2][2];
    v4f  vA[2], vB[2];
    ld_tile(kr, vsr, 0, l15, quad, kA, vA);
#pragma unroll
    for (int tt = 0; tt < 8; tt++) {
        ld_tile(kr, vsr, (2 * tt + 1) & 15, l15, quad, kB, vB);
        tile_compute(kA, vA, qf, osum, lsum);
        ld_tile(kr, vsr, (2 * tt + 2) & 15, l15, quad, kA, vA);
        tile_compute(kB, vB, qf, osum, lsum);
    }

    // epilogue: reduce over key-quads; bvs added outside the softmax
#pragma unroll
    for (int nt = 0; nt < 2; nt++) {
        float lv = lsum[nt];
        lv += __shfl_xor(lv, 16);
        lv += __shfl_xor(lv, 32);
        float ov = osum[nt];
        ov += __shfl_xor(ov, 16);
        ov += __shfl_xor(ov, 32);
        if (quad == 0) out[qrow0 + nt * 16 + l15] = ov / lv + bvs;
    }
}

extern "C" void kernel_launch(void* const* d_in, const int* in_sizes, int n_in,
                              void* d_out, int out_size, void* d_ws, size_t ws_size,
                              hipStream_t stream) {
    const float* power = (const float*)d_in[0];
    const int*   ele_i = (const int*)d_in[1];
    // d_in[2] = range_indices: unused by the reference (positional reshape)
    const int*   azi_i = (const int*)d_in[3];
    const float* ele_t = (const float*)d_in[4];
    const float* azi_t = (const float*)d_in[5];
    const float* Wq = (const float*)d_in[6];
    const float* bq = (const float*)d_in[7];
    const float* Wk = (const float*)d_in[8];
    const float* bk = (const float*)d_in[9];
    const float* Wv = (const float*)d_in[10];
    const float* bv = (const float*)d_in[11];
    float* out = (float*)d_out;

    char*  Kf  = (char*)d_ws;                                  // 256 x 64 KB = 16 MB
    float* vsg = (float*)((char*)d_ws + 16777216);             // 512 KB
    float* wvs = (float*)((char*)d_ws + 16777216 + 524288);    // 97 f32

    sda_colsum<<<1, 128, 0, stream>>>(Wv, bv, wvs);
    sda_proj<<<512, 512, 0, stream>>>(power, ele_i, azi_i, ele_t, azi_t,
                                      Wk, bk, wvs, Kf, vsg);
    sda_attn<<<1024, 256, 0, stream>>>(power, ele_i, azi_i, ele_t, azi_t,
                                       Wq, bq, wvs, Kf, vsg, out);
}

// Round 8
// 258.648 us; speedup vs baseline: 1.1693x; 1.1693x over previous
//
#include <hip/hip_runtime.h>

// SparseDopplerAttention on gfx950 — R8.
// Identity (R3): out[q] = (sum_k P[q,k]*vsum[k])/(sum_k P[q,k]) + sum(bv),
//   vsum[k] = x[k].colsum(Wv) in fp32; V GEMM and PV GEMM eliminated.
// R8 = R3 structure (single kernel, 256 blocks x 1024 thr, 1 blk/CU, best 49.5us)
// + scatter-load fix: Wq/Wk staged ONCE per block into LDS via coalesced
// float4 loads (bf16, XOR-swizzled, 256B row stride) -> per-wave fragment
// reads become conflict-free ds_read_b128 instead of 16-segment global
// scatters (theory: TA serialization made Phase A ~40us of the 49.5).
// Phase B fully unrolled (compile-time LDS offsets). No helper fns, no
// dynamic-indexed register arrays (R4/R7 spill lessons).

#define SCALE 0.18033688011112042f   // log2(e)/8

typedef __bf16 bf16;
typedef bf16 v4bf __attribute__((ext_vector_type(4)));
typedef bf16 v8bf __attribute__((ext_vector_type(8)));
typedef float v4f __attribute__((ext_vector_type(4)));

static __device__ __forceinline__ v8bf pk8(float4 a, float4 b) {
    v8bf r;
    r[0] = (bf16)a.x; r[1] = (bf16)a.y; r[2] = (bf16)a.z; r[3] = (bf16)a.w;
    r[4] = (bf16)b.x; r[5] = (bf16)b.y; r[6] = (bf16)b.z; r[7] = (bf16)b.w;
    return r;
}
static __device__ __forceinline__ v4bf pk4(float4 a) {
    v4bf r;
    r[0] = (bf16)a.x; r[1] = (bf16)a.y; r[2] = (bf16)a.z; r[3] = (bf16)a.w;
    return r;
}
static __device__ __forceinline__ float d4(float4 a, const float* w) {
    return a.x * w[0] + a.y * w[1] + a.z * w[2] + a.w * w[3];
}

// LDS map (dynamic, 100864 B total):
//   Kb   @ 0      : 64 KB  K [key][dim] bf16, 128 B rows, blk16 ^= key&7
//                   (first 3 KB transiently = colsum partials; per-wave 4 KB
//                    slices transiently = Q-transpose scratch)
//   Wl   @ 65536  : 32 KB  Wq (16 KB) then Wk (16 KB): bf16, 256 B row
//                   stride, byte = r*256 + (((kt*4+sg)^(r&7))<<4) + (c&7)*2
//   vsum @ 98304  : 2 KB   512 f32
#define KB_OFF   0
#define WL_OFF   65536
#define VS_OFF   98304

__global__ __launch_bounds__(1024, 4)
void sda_kernel(const float* __restrict__ power,
                const int*   __restrict__ ele_i,
                const int*   __restrict__ azi_i,
                const float* __restrict__ ele_t,
                const float* __restrict__ azi_t,
                const float* __restrict__ Wq, const float* __restrict__ bq,
                const float* __restrict__ Wk, const float* __restrict__ bk,
                const float* __restrict__ Wv, const float* __restrict__ bv,
                float* __restrict__ out)
{
    extern __shared__ char smem[];
    char*  Kb   = smem + KB_OFF;
    float* vsum = (float*)(smem + VS_OFF);
    float* wvp  = (float*)smem;          // transient colsum partials [8][96]

    const int tid  = threadIdx.x;
    const int wave = tid >> 6;
    const int lane = tid & 63;
    const int l15  = lane & 15;
    const int quad = lane >> 4;
    const int range = blockIdx.x;
    const int krow0 = range * 512 + wave * 32;

    // ---- bvs = sum(bv): per-wave shuffle reduce (added after softmax avg) ----
    float bvs = bv[lane];
#pragma unroll
    for (int d = 1; d < 64; d <<= 1) bvs += __shfl_xor(bvs, d);

    // ---- stage Wq,Wk -> LDS (coalesced f4 reads, bf16 swizzled writes) ----
#pragma unroll
    for (int i = 0; i < 3; i++) {
        int f   = tid + i * 1024;            // 0..3071 over [Wq | Wk] float4s
        int mat = (f >= 1536) ? 1 : 0;
        int fl  = f - mat * 1536;
        int row = fl / 24;
        int c4  = fl - row * 24;
        const float* src = (mat ? Wk : Wq) + row * 96 + c4 * 4;
        float4 v = *(const float4*)src;
        int c  = c4 * 4;
        int kt = c >> 5;
        int sg = (c >> 3) & 3;
        int off = WL_OFF + mat * 16384 + row * 256 +
                  ((((kt * 4 + sg) ^ (row & 7)) << 4) | ((c & 7) * 2));
        *(v4bf*)(smem + off) = pk4(v);
    }

    // ---- colsum(Wv) partials: 768 threads x 8 rows (coalesced) ----
    if (tid < 768) {
        int grp = tid / 96, col = tid - grp * 96;
        const float* p = Wv + grp * 8 * 96 + col;
        float s = 0.f;
#pragma unroll
        for (int r = 0; r < 8; r++) s += p[r * 96];
        wvp[grp * 96 + col] = s;
    }
    __syncthreads();
    __shared__ float wvs[96];
    if (tid < 96) {
        float s = 0.f;
#pragma unroll
        for (int g = 0; g < 8; g++) s += wvp[g * 96 + tid];
        wvs[tid] = s;
    }
    __syncthreads();   // wvs ready; wvp dead (Kb scratch free for Q transpose)

    // ---- x fragments (bf16) + fp32 vsum for this wave's 32 rows ----
    v8bf xa[2][3];
#pragma unroll
    for (int mt = 0; mt < 2; mt++) {
        int row = krow0 + mt * 16 + l15;
        const float* pr = power + (size_t)row * 64;
        float4 a0 = *(const float4*)(pr + quad * 8);
        float4 a1 = *(const float4*)(pr + quad * 8 + 4);
        float dd = d4(a0, wvs + quad * 8) + d4(a1, wvs + quad * 8 + 4);
        xa[mt][0] = pk8(a0, a1);
        a0 = *(const float4*)(pr + 32 + quad * 8);
        a1 = *(const float4*)(pr + 32 + quad * 8 + 4);
        dd += d4(a0, wvs + 32 + quad * 8) + d4(a1, wvs + 32 + quad * 8 + 4);
        xa[mt][1] = pk8(a0, a1);
        int ie = ele_i[row];
        int ia = azi_i[row];
        const float* tb = (quad < 2) ? (ele_t + ie * 16 + quad * 8)
                                     : (azi_t + ia * 16 + (quad - 2) * 8);
        a0 = *(const float4*)tb;
        a1 = *(const float4*)(tb + 4);
        dd += d4(a0, wvs + 64 + quad * 8) + d4(a1, wvs + 64 + quad * 8 + 4);
        xa[mt][2] = pk8(a0, a1);
        dd += __shfl_xor(dd, 16);
        dd += __shfl_xor(dd, 32);
        if (quad == 0) vsum[wave * 32 + mt * 16 + l15] = dd;
    }

    // ---- Q^T = Wq @ xa^T (W frags from LDS), fold SCALE, LDS transpose ----
    char* Sw = Kb + wave * 4096;           // wave's own K slice as scratch
    const int wbase = WL_OFF + l15 * 256;  // (r&7)==(l15&7) for r=mtd*16+l15
#pragma unroll
    for (int mtd = 0; mtd < 4; mtd++) {
        v8bf wq0 = *(const v8bf*)(smem + wbase + mtd * 4096 + (((0 + quad) ^ (l15 & 7)) << 4));
        v8bf wq1 = *(const v8bf*)(smem + wbase + mtd * 4096 + (((4 + quad) ^ (l15 & 7)) << 4));
        v8bf wq2 = *(const v8bf*)(smem + wbase + mtd * 4096 + (((8 + quad) ^ (l15 & 7)) << 4));
        v4f acc0 = {0.f, 0.f, 0.f, 0.f};
        v4f acc1 = {0.f, 0.f, 0.f, 0.f};
        acc0 = __builtin_amdgcn_mfma_f32_16x16x32_bf16(wq0, xa[0][0], acc0, 0, 0, 0);
        acc1 = __builtin_amdgcn_mfma_f32_16x16x32_bf16(wq0, xa[1][0], acc1, 0, 0, 0);
        acc0 = __builtin_amdgcn_mfma_f32_16x16x32_bf16(wq1, xa[0][1], acc0, 0, 0, 0);
        acc1 = __builtin_amdgcn_mfma_f32_16x16x32_bf16(wq1, xa[1][1], acc1, 0, 0, 0);
        acc0 = __builtin_amdgcn_mfma_f32_16x16x32_bf16(wq2, xa[0][2], acc0, 0, 0, 0);
        acc1 = __builtin_amdgcn_mfma_f32_16x16x32_bf16(wq2, xa[1][2], acc1, 0, 0, 0);
        float4 bq4 = *(const float4*)(bq + mtd * 16 + quad * 4);
#pragma unroll
        for (int nt = 0; nt < 2; nt++) {
            v4f acc = nt ? acc1 : acc0;
            int row = nt * 16 + l15;
            v4bf o;
            o[0] = (bf16)((acc[0] + bq4.x) * SCALE);
            o[1] = (bf16)((acc[1] + bq4.y) * SCALE);
            o[2] = (bf16)((acc[2] + bq4.z) * SCALE);
            o[3] = (bf16)((acc[3] + bq4.w) * SCALE);
            *(v4bf*)(Sw + row * 128 +
                     ((((mtd * 2 + (quad >> 1)) ^ (row & 7)) << 4) | ((quad & 1) << 3))) = o;
        }
    }
    v8bf qf[2][2];
#pragma unroll
    for (int nt = 0; nt < 2; nt++)
#pragma unroll
        for (int kt = 0; kt < 2; kt++)
            qf[nt][kt] = *(const v8bf*)(Sw + (nt * 16 + l15) * 128 +
                                        (((kt * 4 + quad) ^ (l15 & 7)) << 4));

    // ---- K^T = Wk @ xa^T (W frags from LDS), overwrite scratch ----
#pragma unroll
    for (int mtd = 0; mtd < 4; mtd++) {
        v8bf wk0 = *(const v8bf*)(smem + wbase + 16384 + mtd * 4096 + (((0 + quad) ^ (l15 & 7)) << 4));
        v8bf wk1 = *(const v8bf*)(smem + wbase + 16384 + mtd * 4096 + (((4 + quad) ^ (l15 & 7)) << 4));
        v8bf wk2 = *(const v8bf*)(smem + wbase + 16384 + mtd * 4096 + (((8 + quad) ^ (l15 & 7)) << 4));
        v4f acc0 = {0.f, 0.f, 0.f, 0.f};
        v4f acc1 = {0.f, 0.f, 0.f, 0.f};
        acc0 = __builtin_amdgcn_mfma_f32_16x16x32_bf16(wk0, xa[0][0], acc0, 0, 0, 0);
        acc1 = __builtin_amdgcn_mfma_f32_16x16x32_bf16(wk0, xa[1][0], acc1, 0, 0, 0);
        acc0 = __builtin_amdgcn_mfma_f32_16x16x32_bf16(wk1, xa[0][1], acc0, 0, 0, 0);
        acc1 = __builtin_amdgcn_mfma_f32_16x16x32_bf16(wk1, xa[1][1], acc1, 0, 0, 0);
        acc0 = __builtin_amdgcn_mfma_f32_16x16x32_bf16(wk2, xa[0][2], acc0, 0, 0, 0);
        acc1 = __builtin_amdgcn_mfma_f32_16x16x32_bf16(wk2, xa[1][2], acc1, 0, 0, 0);
        float4 bk4 = *(const float4*)(bk + mtd * 16 + quad * 4);
#pragma unroll
        for (int ntr = 0; ntr < 2; ntr++) {
            v4f acc = ntr ? acc1 : acc0;
            int keyb = wave * 32 + ntr * 16 + l15;
            v4bf o;
            o[0] = (bf16)(acc[0] + bk4.x);
            o[1] = (bf16)(acc[1] + bk4.y);
            o[2] = (bf16)(acc[2] + bk4.z);
            o[3] = (bf16)(acc[3] + bk4.w);
            *(v4bf*)(Kb + keyb * 128 +
                     ((((mtd * 2 + (quad >> 1)) ^ (keyb & 7)) << 4) | ((quad & 1) << 3))) = o;
        }
    }
    __syncthreads();

    // ---- Phase B: S^T = K @ Q^T (log2 domain), exp2, weighted accumulate.
    // Fully unrolled: all LDS offsets compile-time; scheduler free to hoist.
    float osum0 = 0.f, lsum0 = 0.f, osum1 = 0.f, lsum1 = 0.f;
    const int kbase = l15 * 128;           // (key&7) == (l15&7)
#pragma unroll
    for (int t = 0; t < 16; t++) {
#pragma unroll
        for (int mtk = 0; mtk < 2; mtk++) {
            v8bf kf0 = *(const v8bf*)(Kb + kbase + t * 4096 + mtk * 2048 +
                                      (((0 + quad) ^ (l15 & 7)) << 4));
            v8bf kf1 = *(const v8bf*)(Kb + kbase + t * 4096 + mtk * 2048 +
                                      (((4 + quad) ^ (l15 & 7)) << 4));
            v4f vs = *(const v4f*)(vsum + t * 32 + mtk * 16 + quad * 4);
            v4f a0 = {0.f, 0.f, 0.f, 0.f};
            a0 = __builtin_amdgcn_mfma_f32_16x16x32_bf16(kf0, qf[0][0], a0, 0, 0, 0);
            a0 = __builtin_amdgcn_mfma_f32_16x16x32_bf16(kf1, qf[0][1], a0, 0, 0, 0);
            v4f a1 = {0.f, 0.f, 0.f, 0.f};
            a1 = __builtin_amdgcn_mfma_f32_16x16x32_bf16(kf0, qf[1][0], a1, 0, 0, 0);
            a1 = __builtin_amdgcn_mfma_f32_16x16x32_bf16(kf1, qf[1][1], a1, 0, 0, 0);
            float p0 = __builtin_amdgcn_exp2f(a0[0]);
            float p1 = __builtin_amdgcn_exp2f(a0[1]);
            float p2 = __builtin_amdgcn_exp2f(a0[2]);
            float p3 = __builtin_amdgcn_exp2f(a0[3]);
            lsum0 += (p0 + p1) + (p2 + p3);
            osum0 += ((p0 * vs[0] + p1 * vs[1]) + (p2 * vs[2] + p3 * vs[3]));
            p0 = __builtin_amdgcn_exp2f(a1[0]);
            p1 = __builtin_amdgcn_exp2f(a1[1]);
            p2 = __builtin_amdgcn_exp2f(a1[2]);
            p3 = __builtin_amdgcn_exp2f(a1[3]);
            lsum1 += (p0 + p1) + (p2 + p3);
            osum1 += ((p0 * vs[0] + p1 * vs[1]) + (p2 * vs[2] + p3 * vs[3]));
        }
    }

    // ---- epilogue: reduce over key-quads; bvs added outside the softmax ----
#pragma unroll
    for (int nt = 0; nt < 2; nt++) {
        float lv = nt ? lsum1 : lsum0;
        lv += __shfl_xor(lv, 16);
        lv += __shfl_xor(lv, 32);
        float ov = nt ? osum1 : osum0;
        ov += __shfl_xor(ov, 16);
        ov += __shfl_xor(ov, 32);
        if (quad == 0) out[krow0 + nt * 16 + l15] = ov / lv + bvs;
    }
}

extern "C" void kernel_launch(void* const* d_in, const int* in_sizes, int n_in,
                              void* d_out, int out_size, void* d_ws, size_t ws_size,
                              hipStream_t stream) {
    const float* power = (const float*)d_in[0];
    const int*   ele_i = (const int*)d_in[1];
    // d_in[2] = range_indices: unused by the reference (positional reshape)
    const int*   azi_i = (const int*)d_in[3];
    const float* ele_t = (const float*)d_in[4];
    const float* azi_t = (const float*)d_in[5];
    const float* Wq = (const float*)d_in[6];
    const float* bq = (const float*)d_in[7];
    const float* Wk = (const float*)d_in[8];
    const float* bk = (const float*)d_in[9];
    const float* Wv = (const float*)d_in[10];
    const float* bv = (const float*)d_in[11];
    float* out = (float*)d_out;

    const int lds_bytes = 100864;   // Kb 64K + Wl 32K + vsum 2K + pad
    (void)hipFuncSetAttribute(reinterpret_cast<const void*>(sda_kernel),
                              hipFuncAttributeMaxDynamicSharedMemorySize, lds_bytes);
    sda_kernel<<<256, 1024, lds_bytes, stream>>>(power, ele_i, azi_i, ele_t, azi_t,
                                                 Wq, bq, Wk, bk, Wv, bv, out);
}